// Round 1
// baseline (202.451 us; speedup 1.0000x reference)
//
#include <hip/hip_runtime.h>
#include <math.h>

#define BS 640
#define IN_CH 2048
#define NGRP 174
#define OUT_CH 696
#define CHUNK 320
#define EPS_BN 1e-5f
#define LOG2E 1.4426950408889634f

#if __has_builtin(__builtin_amdgcn_exp2f)
#define EXP2(x) __builtin_amdgcn_exp2f(x)
#else
#define EXP2(x) exp2f(x)
#endif

// ---------------- zero-fill (split-K accumulator init; avoids hipMemsetAsync) ----
__global__ __launch_bounds__(256) void zero_kernel(float4* __restrict__ p, int n4) {
    int i = blockIdx.x * 256 + threadIdx.x;
    if (i < n4) p[i] = make_float4(0.f, 0.f, 0.f, 0.f);
}

// ---------------- GEMM: H[640][696] += x[640][2048] @ w[696][2048]^T ------------
// 64x64 tile, BK=16, split-K=4 via f32 atomics. grid (10, 11, 4), block 256.
__global__ __launch_bounds__(256) void gemm_kernel(const float* __restrict__ X,
                                                   const float* __restrict__ W,
                                                   float* __restrict__ H) {
    const int BM = 64, BN = 64, BK = 16;
    __shared__ float As[BK][BM + 4];
    __shared__ float Bs[BK][BN + 4];
    int tid = threadIdx.x;
    int tx = tid & 15, ty = tid >> 4;
    int row0 = blockIdx.x * BM;
    int col0 = blockIdx.y * BN;
    int k0 = blockIdx.z * (IN_CH / 4);   // 512-wide K slice per z
    int lr = tid >> 2;                    // 0..63 : tile row
    int lc = (tid & 3) << 2;              // 0,4,8,12 : k sub-offset
    float acc[4][4] = {};
    const float* xp = X + (size_t)(row0 + lr) * IN_CH + k0 + lc;
    int wn = col0 + lr;
    bool wok = (wn < OUT_CH);
    const float* wp = W + (size_t)(wok ? wn : 0) * IN_CH + k0 + lc;

    for (int kt = 0; kt < IN_CH / 4; kt += BK) {
        float4 a4 = *(const float4*)(xp + kt);
        float4 b4 = wok ? *(const float4*)(wp + kt) : make_float4(0.f, 0.f, 0.f, 0.f);
        __syncthreads();
        As[lc + 0][lr] = a4.x; As[lc + 1][lr] = a4.y; As[lc + 2][lr] = a4.z; As[lc + 3][lr] = a4.w;
        Bs[lc + 0][lr] = b4.x; Bs[lc + 1][lr] = b4.y; Bs[lc + 2][lr] = b4.z; Bs[lc + 3][lr] = b4.w;
        __syncthreads();
#pragma unroll
        for (int k = 0; k < BK; ++k) {
            float4 av = *(const float4*)(&As[k][ty << 2]);
            float4 bv = *(const float4*)(&Bs[k][tx << 2]);
            float a_[4] = {av.x, av.y, av.z, av.w};
            float b_[4] = {bv.x, bv.y, bv.z, bv.w};
#pragma unroll
            for (int i = 0; i < 4; ++i)
#pragma unroll
                for (int j = 0; j < 4; ++j)
                    acc[i][j] = fmaf(a_[i], b_[j], acc[i][j]);
        }
    }
#pragma unroll
    for (int i = 0; i < 4; ++i) {
        int r = row0 + (ty << 2) + i;
#pragma unroll
        for (int j = 0; j < 4; ++j) {
            int c = col0 + (tx << 2) + j;
            if (c < OUT_CH) atomicAdd(&H[(size_t)r * OUT_CH + c], acc[i][j]);
        }
    }
}

// ---------------- fused: GhostBN(stats+apply) + prior-mul + qkv + channelwise
//                  softmax-attention + out_proj + residual. In-place on H. -------
// grid (174 groups, 2 chunks), block 320 (one thread per query row l in chunk).
__global__ __launch_bounds__(320) void attn_kernel(float* H,
        const float* __restrict__ prior,
        const float* __restrict__ gamma, const float* __restrict__ beta,
        const float* __restrict__ ipw, const float* __restrict__ ipb,
        const float* __restrict__ opw, const float* __restrict__ opb) {
    __shared__ float k_sh[BS][4];
    __shared__ float v_sh[BS][4];
    __shared__ float red[5][8];   // per-wave partial sums: sum[4], sumsq[4]
    __shared__ float kext[8];     // kmax[4], kmin[4]

    int n = blockIdx.x;
    int chunk = blockIdx.y;
    int tid = threadIdx.x;
    int c0 = n * 4;

    // ---- k, v from prior rows (full s range), staged to LDS ----
    for (int s = tid; s < BS; s += 320) {
        float4 pr = *(const float4*)(prior + (size_t)s * OUT_CH + c0);
        float p_[4] = {pr.x, pr.y, pr.z, pr.w};
        float kk[4], vv[4];
#pragma unroll
        for (int e = 0; e < 4; ++e) {
            float ak = ipb[4 + e], av = ipb[8 + e];
#pragma unroll
            for (int e2 = 0; e2 < 4; ++e2) {
                ak = fmaf(ipw[(4 + e) * 4 + e2], p_[e2], ak);
                av = fmaf(ipw[(8 + e) * 4 + e2], p_[e2], av);
            }
            kk[e] = ak; vv[e] = av;
        }
        *(float4*)&k_sh[s][0] = make_float4(kk[0], kk[1], kk[2], kk[3]);
        *(float4*)&v_sh[s][0] = make_float4(vv[0], vv[1], vv[2], vv[3]);
    }

    // ---- this thread's query row: raw h, prior ----
    int l = chunk * CHUNK + tid;
    float4 h4 = *(const float4*)(H + (size_t)l * OUT_CH + c0);
    float4 pq = *(const float4*)(prior + (size_t)l * OUT_CH + c0);
    float hraw[4] = {h4.x, h4.y, h4.z, h4.w};
    float pq_[4] = {pq.x, pq.y, pq.z, pq.w};

    // ---- GhostBN stats over this (chunk, 4 channels): block reduce ----
    float rv[8];
#pragma unroll
    for (int e = 0; e < 4; ++e) { rv[e] = hraw[e]; rv[4 + e] = hraw[e] * hraw[e]; }
#pragma unroll
    for (int off = 32; off > 0; off >>= 1)
#pragma unroll
        for (int j = 0; j < 8; ++j) rv[j] += __shfl_down(rv[j], off);
    int wv = tid >> 6, ln = tid & 63;
    if (ln == 0)
#pragma unroll
        for (int j = 0; j < 8; ++j) red[wv][j] = rv[j];
    __syncthreads();   // covers k_sh/v_sh stores + red stores

    // ---- kmax/kmin per e (waves 0..3) ----
    if (wv < 4) {
        float mx = -3e38f, mn = 3e38f;
        for (int s = ln; s < BS; s += 64) { float kv = k_sh[s][wv]; mx = fmaxf(mx, kv); mn = fminf(mn, kv); }
#pragma unroll
        for (int off = 32; off > 0; off >>= 1) {
            mx = fmaxf(mx, __shfl_down(mx, off));
            mn = fminf(mn, __shfl_down(mn, off));
        }
        if (ln == 0) { kext[wv] = mx; kext[4 + wv] = mn; }
    }
    __syncthreads();

    // ---- finish stats (uniform LDS broadcast), BN-apply + prior mul ----
    float sums[8];
#pragma unroll
    for (int j = 0; j < 8; ++j)
        sums[j] = red[0][j] + red[1][j] + red[2][j] + red[3][j] + red[4][j];
    float hh[4];
#pragma unroll
    for (int e = 0; e < 4; ++e) {
        float m = sums[e] * (1.0f / CHUNK);
        float var = sums[4 + e] * (1.0f / CHUNK) - m * m;
        float rs = rsqrtf(var + EPS_BN);
        hh[e] = (fmaf(hraw[e] - m, rs * gamma[c0 + e], beta[c0 + e])) * pq_[e];
    }

    // ---- q (folded with log2e), stabilizer from k extrema ----
    float q2[4], tmax[4];
#pragma unroll
    for (int e = 0; e < 4; ++e) {
        float q = ipb[e];
#pragma unroll
        for (int e2 = 0; e2 < 4; ++e2) q = fmaf(ipw[e * 4 + e2], hh[e2], q);
        q2[e] = q * LOG2E;
        tmax[e] = (q2[e] > 0.f) ? q2[e] * kext[e] : q2[e] * kext[4 + e];
    }

    // ---- the 640-deep softmax-weighted average, 4 channels interleaved ----
    float sum[4] = {0.f, 0.f, 0.f, 0.f}, accv[4] = {0.f, 0.f, 0.f, 0.f};
    for (int s = 0; s < BS; ++s) {
        float4 kv = *(const float4*)&k_sh[s][0];
        float4 vv = *(const float4*)&v_sh[s][0];
        float w0 = EXP2(fmaf(q2[0], kv.x, -tmax[0]));
        float w1 = EXP2(fmaf(q2[1], kv.y, -tmax[1]));
        float w2 = EXP2(fmaf(q2[2], kv.z, -tmax[2]));
        float w3 = EXP2(fmaf(q2[3], kv.w, -tmax[3]));
        sum[0] += w0; accv[0] = fmaf(w0, vv.x, accv[0]);
        sum[1] += w1; accv[1] = fmaf(w1, vv.y, accv[1]);
        sum[2] += w2; accv[2] = fmaf(w2, vv.z, accv[2]);
        sum[3] += w3; accv[3] = fmaf(w3, vv.w, accv[3]);
    }

    // ---- out_proj + residual, in-place write ----
    float o[4];
#pragma unroll
    for (int e = 0; e < 4; ++e) o[e] = accv[e] / sum[e];
    float y[4];
#pragma unroll
    for (int e = 0; e < 4; ++e) {
        float a = opb[e];
#pragma unroll
        for (int e2 = 0; e2 < 4; ++e2) a = fmaf(opw[e * 4 + e2], o[e2], a);
        y[e] = a;
    }
    *(float4*)(H + (size_t)l * OUT_CH + c0) =
        make_float4(hh[0] + y[0], hh[1] + y[1], hh[2] + y[2], hh[3] + y[3]);
}

// ---------------- final row softmax over 696 channels, in-place ------------------
__global__ __launch_bounds__(256) void softmax_kernel(float* __restrict__ out) {
    __shared__ float red[4];
    int row = blockIdx.x;
    float* p = out + (size_t)row * OUT_CH;
    int tid = threadIdx.x;
    float v[3] = {-3e38f, -3e38f, -3e38f};
#pragma unroll
    for (int i = 0; i < 3; ++i) { int c = tid + i * 256; if (c < OUT_CH) v[i] = p[c]; }
    float mx = fmaxf(fmaxf(v[0], v[1]), v[2]);
#pragma unroll
    for (int off = 32; off > 0; off >>= 1) mx = fmaxf(mx, __shfl_down(mx, off));
    if ((tid & 63) == 0) red[tid >> 6] = mx;
    __syncthreads();
    mx = fmaxf(fmaxf(red[0], red[1]), fmaxf(red[2], red[3]));
    __syncthreads();
    float e[3] = {0.f, 0.f, 0.f};
    float s = 0.f;
#pragma unroll
    for (int i = 0; i < 3; ++i) {
        int c = tid + i * 256;
        if (c < OUT_CH) { e[i] = EXP2((v[i] - mx) * LOG2E); s += e[i]; }
    }
#pragma unroll
    for (int off = 32; off > 0; off >>= 1) s += __shfl_down(s, off);
    if ((tid & 63) == 0) red[tid >> 6] = s;
    __syncthreads();
    s = red[0] + red[1] + red[2] + red[3];
    float inv = 1.0f / s;
#pragma unroll
    for (int i = 0; i < 3; ++i) { int c = tid + i * 256; if (c < OUT_CH) p[c] = e[i] * inv; }
}

extern "C" void kernel_launch(void* const* d_in, const int* in_sizes, int n_in,
                              void* d_out, int out_size, void* d_ws, size_t ws_size,
                              hipStream_t stream) {
    const float* x     = (const float*)d_in[0];
    const float* prior = (const float*)d_in[1];
    const float* w_lin = (const float*)d_in[2];
    const float* gamma = (const float*)d_in[3];
    const float* beta  = (const float*)d_in[4];
    const float* ipw   = (const float*)d_in[5];
    const float* ipb   = (const float*)d_in[6];
    const float* opw   = (const float*)d_in[7];
    const float* opb   = (const float*)d_in[8];
    float* out = (float*)d_out;

    int n4 = (BS * OUT_CH) / 4;  // 111360, divisible by 4
    zero_kernel<<<(n4 + 255) / 256, 256, 0, stream>>>((float4*)out, n4);
    gemm_kernel<<<dim3(10, 11, 4), 256, 0, stream>>>(x, w_lin, out);
    attn_kernel<<<dim3(NGRP, 2), 320, 0, stream>>>(out, prior, gamma, beta, ipw, ipb, opw, opb);
    softmax_kernel<<<BS, 256, 0, stream>>>(out);
}

// Round 2
// 149.182 us; speedup vs baseline: 1.3571x; 1.3571x over previous
//
#include <hip/hip_runtime.h>
#include <math.h>

#define BS 640
#define IN_CH 2048
#define NGRP 174
#define OUT_CH 696
#define CHUNK 320
#define EPS_BN 1e-5f
#define LOG2E 1.4426950408889634f

#if __has_builtin(__builtin_amdgcn_exp2f)
#define EXP2(x) __builtin_amdgcn_exp2f(x)
#else
#define EXP2(x) exp2f(x)
#endif

typedef short short8 __attribute__((ext_vector_type(8)));
typedef float f32x4 __attribute__((ext_vector_type(4)));

// ---------------- zero-fill (split-K accumulator init) ---------------------------
__global__ __launch_bounds__(256) void zero_kernel(float4* __restrict__ p, int n4) {
    int i = blockIdx.x * 256 + threadIdx.x;
    if (i < n4) p[i] = make_float4(0.f, 0.f, 0.f, 0.f);
}

// f32 -> bf16 hi (RNE) + bf16 lo (RNE of residual)
__device__ inline void split_bf16(float x, unsigned short* hi, unsigned short* lo) {
    unsigned int u = __float_as_uint(x);
    unsigned int rh = (u + 0x7FFFu + ((u >> 16) & 1u)) >> 16;
    *hi = (unsigned short)rh;
    float hf = __uint_as_float(rh << 16);
    float l = x - hf;
    unsigned int ul = __float_as_uint(l);
    *lo = (unsigned short)((ul + 0x7FFFu + ((ul >> 16) & 1u)) >> 16);
}

// ---------------- GEMM: H += x @ w^T via split-bf16 MFMA -------------------------
// 64x64 tile, BK=64, split-K=4 (z), f32 atomics. grid (10,11,4), block 256 (4 waves 2x2).
__global__ __launch_bounds__(256) void gemm_kernel(const float* __restrict__ X,
                                                   const float* __restrict__ W,
                                                   float* __restrict__ H) {
    __shared__ unsigned short Ah[64][72], Al[64][72], Bh[64][72], Bl[64][72];
    int tid = threadIdx.x;
    int row0 = blockIdx.x * 64;
    int col0 = blockIdx.y * 64;
    int k0 = blockIdx.z * (IN_CH / 4);

    int srow = tid >> 2;            // 0..63
    int skc = (tid & 3) * 16;       // 0,16,32,48
    const float* xp = X + (size_t)(row0 + srow) * IN_CH + k0 + skc;
    int wn = col0 + srow;
    const float* wp = W + (size_t)(wn < OUT_CH ? wn : 0) * IN_CH + k0 + skc;

    int w = tid >> 6;
    int lane = tid & 63;
    int wr = (w >> 1) * 32, wc = (w & 1) * 32;
    int lr = lane & 15, lq = lane >> 4;

    f32x4 acc[2][2] = {};

    for (int kt = 0; kt < IN_CH / 4; kt += 64) {
        float4 a[4], b[4];
#pragma unroll
        for (int i = 0; i < 4; ++i) {
            a[i] = *(const float4*)(xp + kt + 4 * i);
            b[i] = *(const float4*)(wp + kt + 4 * i);
        }
        __syncthreads();   // previous iteration's LDS reads complete
#pragma unroll
        for (int i = 0; i < 4; ++i) {
            float av[4] = {a[i].x, a[i].y, a[i].z, a[i].w};
            float bv[4] = {b[i].x, b[i].y, b[i].z, b[i].w};
            unsigned short ah[4], al[4], bh[4], bl[4];
#pragma unroll
            for (int j = 0; j < 4; ++j) {
                split_bf16(av[j], &ah[j], &al[j]);
                split_bf16(bv[j], &bh[j], &bl[j]);
            }
            *(ushort4*)&Ah[srow][skc + 4 * i] = make_ushort4(ah[0], ah[1], ah[2], ah[3]);
            *(ushort4*)&Al[srow][skc + 4 * i] = make_ushort4(al[0], al[1], al[2], al[3]);
            *(ushort4*)&Bh[srow][skc + 4 * i] = make_ushort4(bh[0], bh[1], bh[2], bh[3]);
            *(ushort4*)&Bl[srow][skc + 4 * i] = make_ushort4(bl[0], bl[1], bl[2], bl[3]);
        }
        __syncthreads();
#pragma unroll
        for (int kk = 0; kk < 64; kk += 32) {
            int ko = kk + lq * 8;
            short8 ahf[2], alf[2], bhf[2], blf[2];
#pragma unroll
            for (int mf = 0; mf < 2; ++mf) {
                ahf[mf] = *(const short8*)&Ah[wr + mf * 16 + lr][ko];
                alf[mf] = *(const short8*)&Al[wr + mf * 16 + lr][ko];
                bhf[mf] = *(const short8*)&Bh[wc + mf * 16 + lr][ko];
                blf[mf] = *(const short8*)&Bl[wc + mf * 16 + lr][ko];
            }
#pragma unroll
            for (int mf = 0; mf < 2; ++mf)
#pragma unroll
                for (int nf = 0; nf < 2; ++nf) {
                    acc[mf][nf] = __builtin_amdgcn_mfma_f32_16x16x32_bf16(ahf[mf], bhf[nf], acc[mf][nf], 0, 0, 0);
                    acc[mf][nf] = __builtin_amdgcn_mfma_f32_16x16x32_bf16(ahf[mf], blf[nf], acc[mf][nf], 0, 0, 0);
                    acc[mf][nf] = __builtin_amdgcn_mfma_f32_16x16x32_bf16(alf[mf], bhf[nf], acc[mf][nf], 0, 0, 0);
                }
        }
    }
#pragma unroll
    for (int mf = 0; mf < 2; ++mf)
#pragma unroll
        for (int nf = 0; nf < 2; ++nf)
#pragma unroll
            for (int j = 0; j < 4; ++j) {
                int r = row0 + wr + mf * 16 + lq * 4 + j;
                int c = col0 + wc + nf * 16 + lr;
                if (c < OUT_CH) atomicAdd(&H[(size_t)r * OUT_CH + c], acc[mf][nf][j]);
            }
}

// ---------------- GhostBN stats -> folded scale/shift in ws ----------------------
// grid (174, 2), block 320. ws layout: sc[2][696] then sh[2][696] (f32).
__global__ __launch_bounds__(320) void stats_kernel(const float* __restrict__ H,
        const float* __restrict__ gamma, const float* __restrict__ beta,
        float* __restrict__ stats) {
    __shared__ float red[5][8];
    int n = blockIdx.x, chunk = blockIdx.y, tid = threadIdx.x;
    int c0 = n * 4;
    int l = chunk * CHUNK + tid;
    float4 h4 = *(const float4*)(H + (size_t)l * OUT_CH + c0);
    float hr[4] = {h4.x, h4.y, h4.z, h4.w};
    float rv[8];
#pragma unroll
    for (int e = 0; e < 4; ++e) { rv[e] = hr[e]; rv[4 + e] = hr[e] * hr[e]; }
#pragma unroll
    for (int off = 32; off > 0; off >>= 1)
#pragma unroll
        for (int j = 0; j < 8; ++j) rv[j] += __shfl_down(rv[j], off);
    int wv = tid >> 6, ln = tid & 63;
    if (ln == 0)
#pragma unroll
        for (int j = 0; j < 8; ++j) red[wv][j] = rv[j];
    __syncthreads();
    if (tid < 4) {
        int e = tid;
        float s = red[0][e] + red[1][e] + red[2][e] + red[3][e] + red[4][e];
        float ss = red[0][4 + e] + red[1][4 + e] + red[2][4 + e] + red[3][4 + e] + red[4][4 + e];
        float m = s * (1.0f / CHUNK);
        float var = ss * (1.0f / CHUNK) - m * m;
        float scv = rsqrtf(var + EPS_BN) * gamma[c0 + e];
        stats[chunk * OUT_CH + c0 + e] = scv;
        stats[2 * OUT_CH + chunk * OUT_CH + c0 + e] = beta[c0 + e] - m * scv;
    }
}

// ---------------- attention: BN-apply + prior-mul + qkv + softmax-avg + out_proj
// grid (174, 10): group n, 64-query block. block 256: thread = (query, s-segment).
__global__ __launch_bounds__(256) void attn_kernel(float* __restrict__ H,
        const float* __restrict__ prior,
        const float* __restrict__ stats,
        const float* __restrict__ ipw, const float* __restrict__ ipb,
        const float* __restrict__ opw, const float* __restrict__ opb) {
    __shared__ float k_sh[BS][4];
    __shared__ float v_sh[BS][4];
    __shared__ float kext[8];

    int n = blockIdx.x, qb = blockIdx.y, tid = threadIdx.x;
    int c0 = n * 4;
    int chunk = (qb >= 5);

    // stage k/v at seg-interleaved physical index p = (s%160)*4 + s/160
    for (int s = tid; s < BS; s += 256) {
        float4 pr = *(const float4*)(prior + (size_t)s * OUT_CH + c0);
        float p_[4] = {pr.x, pr.y, pr.z, pr.w};
        float kk[4], vv[4];
#pragma unroll
        for (int e = 0; e < 4; ++e) {
            float ak = ipb[4 + e], av = ipb[8 + e];
#pragma unroll
            for (int e2 = 0; e2 < 4; ++e2) {
                ak = fmaf(ipw[(4 + e) * 4 + e2], p_[e2], ak);
                av = fmaf(ipw[(8 + e) * 4 + e2], p_[e2], av);
            }
            kk[e] = ak; vv[e] = av;
        }
        int p = (s % 160) * 4 + (s / 160);
        *(float4*)&k_sh[p][0] = make_float4(kk[0], kk[1], kk[2], kk[3]);
        *(float4*)&v_sh[p][0] = make_float4(vv[0], vv[1], vv[2], vv[3]);
    }
    __syncthreads();

    int wv = tid >> 6, ln = tid & 63;
    if (wv < 4) {
        float mx = -3e38f, mn = 3e38f;
        for (int p = ln; p < BS; p += 64) {
            float kv = k_sh[p][wv];
            mx = fmaxf(mx, kv); mn = fminf(mn, kv);
        }
#pragma unroll
        for (int off = 32; off > 0; off >>= 1) {
            mx = fmaxf(mx, __shfl_down(mx, off));
            mn = fminf(mn, __shfl_down(mn, off));
        }
        if (ln == 0) { kext[wv] = mx; kext[4 + wv] = mn; }
    }
    __syncthreads();

    int q = qb * 64 + (tid >> 2);
    int seg = tid & 3;
    float4 h4 = *(const float4*)(H + (size_t)q * OUT_CH + c0);
    float4 pq = *(const float4*)(prior + (size_t)q * OUT_CH + c0);
    float hr[4] = {h4.x, h4.y, h4.z, h4.w};
    float pq_[4] = {pq.x, pq.y, pq.z, pq.w};
    const float* sc = stats + chunk * OUT_CH;
    const float* sh = stats + 2 * OUT_CH + chunk * OUT_CH;

    float hh[4];
#pragma unroll
    for (int e = 0; e < 4; ++e)
        hh[e] = fmaf(hr[e], sc[c0 + e], sh[c0 + e]) * pq_[e];

    float q2[4], tmax[4];
#pragma unroll
    for (int e = 0; e < 4; ++e) {
        float qv = ipb[e];
#pragma unroll
        for (int e2 = 0; e2 < 4; ++e2) qv = fmaf(ipw[e * 4 + e2], hh[e2], qv);
        q2[e] = qv * LOG2E;
        tmax[e] = (q2[e] > 0.f) ? q2[e] * kext[e] : q2[e] * kext[4 + e];
    }

    float sum[4] = {0.f, 0.f, 0.f, 0.f}, accv[4] = {0.f, 0.f, 0.f, 0.f};
#pragma unroll 4
    for (int i = 0; i < 160; ++i) {
        int p = i * 4 + seg;
        float4 kv = *(const float4*)&k_sh[p][0];
        float4 vv = *(const float4*)&v_sh[p][0];
        float w0 = EXP2(fmaf(q2[0], kv.x, -tmax[0]));
        float w1 = EXP2(fmaf(q2[1], kv.y, -tmax[1]));
        float w2 = EXP2(fmaf(q2[2], kv.z, -tmax[2]));
        float w3 = EXP2(fmaf(q2[3], kv.w, -tmax[3]));
        sum[0] += w0; accv[0] = fmaf(w0, vv.x, accv[0]);
        sum[1] += w1; accv[1] = fmaf(w1, vv.y, accv[1]);
        sum[2] += w2; accv[2] = fmaf(w2, vv.z, accv[2]);
        sum[3] += w3; accv[3] = fmaf(w3, vv.w, accv[3]);
    }
    // combine the 4 s-segments (lanes q*4+0..3, same wave)
#pragma unroll
    for (int d = 1; d < 4; d <<= 1)
#pragma unroll
        for (int e = 0; e < 4; ++e) {
            sum[e] += __shfl_xor(sum[e], d);
            accv[e] += __shfl_xor(accv[e], d);
        }

    if (seg == 0) {
        float o[4], y[4];
#pragma unroll
        for (int e = 0; e < 4; ++e) o[e] = accv[e] / sum[e];
#pragma unroll
        for (int e = 0; e < 4; ++e) {
            float a = opb[e];
#pragma unroll
            for (int e2 = 0; e2 < 4; ++e2) a = fmaf(opw[e * 4 + e2], o[e2], a);
            y[e] = a;
        }
        *(float4*)(H + (size_t)q * OUT_CH + c0) =
            make_float4(hh[0] + y[0], hh[1] + y[1], hh[2] + y[2], hh[3] + y[3]);
    }
}

// ---------------- final row softmax over 696 channels, in-place ------------------
__global__ __launch_bounds__(256) void softmax_kernel(float* __restrict__ out) {
    __shared__ float red[4];
    int row = blockIdx.x;
    float* p = out + (size_t)row * OUT_CH;
    int tid = threadIdx.x;
    float v[3] = {-3e38f, -3e38f, -3e38f};
#pragma unroll
    for (int i = 0; i < 3; ++i) { int c = tid + i * 256; if (c < OUT_CH) v[i] = p[c]; }
    float mx = fmaxf(fmaxf(v[0], v[1]), v[2]);
#pragma unroll
    for (int off = 32; off > 0; off >>= 1) mx = fmaxf(mx, __shfl_down(mx, off));
    if ((tid & 63) == 0) red[tid >> 6] = mx;
    __syncthreads();
    mx = fmaxf(fmaxf(red[0], red[1]), fmaxf(red[2], red[3]));
    __syncthreads();
    float e[3] = {0.f, 0.f, 0.f};
    float s = 0.f;
#pragma unroll
    for (int i = 0; i < 3; ++i) {
        int c = tid + i * 256;
        if (c < OUT_CH) { e[i] = EXP2((v[i] - mx) * LOG2E); s += e[i]; }
    }
#pragma unroll
    for (int off = 32; off > 0; off >>= 1) s += __shfl_down(s, off);
    if ((tid & 63) == 0) red[tid >> 6] = s;
    __syncthreads();
    s = red[0] + red[1] + red[2] + red[3];
    float inv = 1.0f / s;
#pragma unroll
    for (int i = 0; i < 3; ++i) { int c = tid + i * 256; if (c < OUT_CH) p[c] = e[i] * inv; }
}

extern "C" void kernel_launch(void* const* d_in, const int* in_sizes, int n_in,
                              void* d_out, int out_size, void* d_ws, size_t ws_size,
                              hipStream_t stream) {
    const float* x     = (const float*)d_in[0];
    const float* prior = (const float*)d_in[1];
    const float* w_lin = (const float*)d_in[2];
    const float* gamma = (const float*)d_in[3];
    const float* beta  = (const float*)d_in[4];
    const float* ipw   = (const float*)d_in[5];
    const float* ipb   = (const float*)d_in[6];
    const float* opw   = (const float*)d_in[7];
    const float* opb   = (const float*)d_in[8];
    float* out = (float*)d_out;
    float* stats = (float*)d_ws;   // 4*696 f32 = 11136 B

    int n4 = (BS * OUT_CH) / 4;
    zero_kernel<<<(n4 + 255) / 256, 256, 0, stream>>>((float4*)out, n4);
    gemm_kernel<<<dim3(10, 11, 4), 256, 0, stream>>>(x, w_lin, out);
    stats_kernel<<<dim3(NGRP, 2), 320, 0, stream>>>(out, gamma, beta, stats);
    attn_kernel<<<dim3(NGRP, 10), 256, 0, stream>>>(out, prior, stats, ipw, ipb, opw, opb);
    softmax_kernel<<<BS, 256, 0, stream>>>(out);
}